// Round 1
// baseline (417.947 us; speedup 1.0000x reference)
//
#include <hip/hip_runtime.h>
#include <hip/hip_bf16.h>
#include <cstdint>

#define NN 8192
#define F 512
#define LOG2E 1.4426950408889634f

typedef __attribute__((ext_vector_type(8))) short bf16x8;
typedef __attribute__((ext_vector_type(4))) float f32x4;

__device__ __forceinline__ short f2bf(float x){
  __hip_bfloat16 h = __float2bfloat16(x);
  return *reinterpret_cast<short*>(&h);
}

// ---------- wa = W @ a1 / W @ a2 (tiny) ----------
__global__ void k_wa(const float* __restrict__ W, const float* __restrict__ attn,
                     float* __restrict__ wa){
  int b = blockIdx.x;          // 0: a1, 1: a2
  int c = threadIdx.x;         // 0..511 (input-feature index)
  const float* a = attn + b*F;
  float s = 0.f;
  #pragma unroll 8
  for (int k=0;k<F;k++) s = fmaf(W[c*F+k], a[k], s);
  wa[b*F+c] = s;
}

// ---------- s1L/s2L = (X @ wa) * log2(e), one wave per row ----------
__global__ __launch_bounds__(256) void k_s(const float* __restrict__ X, const float* __restrict__ wa,
                    float* __restrict__ s1L, float* __restrict__ s2L){
  int lane = threadIdx.x & 63, wid = threadIdx.x >> 6;
  int row = blockIdx.x*4 + wid;
  const float* x = X + (size_t)row*F;
  float a1=0.f, a2=0.f;
  for (int c=lane;c<F;c+=64){ float xv=x[c]; a1=fmaf(xv,wa[c],a1); a2=fmaf(xv,wa[F+c],a2); }
  for (int off=32;off;off>>=1){ a1 += __shfl_down(a1,off); a2 += __shfl_down(a2,off); }
  if (lane==0){ s1L[row]=a1*LOG2E; s2L[row]=a2*LOG2E; }
}

// ---------- bf16 converts ----------
__global__ void k_cvt_x(const float* __restrict__ X, short* __restrict__ Xb){
  size_t i = ((size_t)blockIdx.x*256 + threadIdx.x)*4;
  float4 v = *(const float4*)(X+i);
  short o[4] = {f2bf(v.x),f2bf(v.y),f2bf(v.z),f2bf(v.w)};
  *(uint2*)(Xb+i) = *(const uint2*)o;
}
__global__ void k_cvt_wT(const float* __restrict__ W, short* __restrict__ WbT){
  int k = blockIdx.x, n = threadIdx.x;
  WbT[n*F+k] = f2bf(W[k*F+n]);
}

// ---------- GEMM1: h = Xb @ WbT^T, writes HT[feature][node] bf16 ----------
// 128x128 tile, BK=64, 4 waves (32 M-rows each), XOR-swizzled LDS tiles.
__global__ __launch_bounds__(256,2) void k_gemm1(const short* __restrict__ Xb,
    const short* __restrict__ WbT, short* __restrict__ HT){
  __shared__ char smem[33280];              // loop: At(16K)+Bt(16K); epilogue: ct 128x130 bf16
  short* At = (short*)smem;
  short* Bt = (short*)(smem + 16384);
  const int tid=threadIdx.x, lane=tid&63, wid=tid>>6;
  const int m0 = blockIdx.x*128, n0 = blockIdx.y*128;
  f32x4 acc[2][8];
  #pragma unroll
  for (int a=0;a<2;++a)
    #pragma unroll
    for (int b=0;b<8;++b) acc[a][b] = (f32x4){0.f,0.f,0.f,0.f};

  for (int t=0;t<8;++t){
    const int k0 = t*64;
    __syncthreads();
    #pragma unroll
    for (int rnd=0;rnd<4;++rnd){
      const int s = rnd*256 + tid;
      const int n = s>>3, kc = s&7;
      uint4 va = *(const uint4*)(Xb  + (size_t)(m0+n)*F + k0 + kc*8);
      uint4 vb = *(const uint4*)(WbT + (size_t)(n0+n)*F + k0 + kc*8);
      const int off = n*128 + ((kc^(n&7))*16);
      *(uint4*)((char*)At + off) = va;
      *(uint4*)((char*)Bt + off) = vb;
    }
    __syncthreads();
    #pragma unroll
    for (int ks=0;ks<2;++ks){
      const int kc = ks*4 + (lane>>4);
      int r0 = wid*32 + (lane&15);
      int r1 = r0 + 16;
      bf16x8 af0 = *(const bf16x8*)((char*)At + r0*128 + ((kc^(r0&7))*16));
      bf16x8 af1 = *(const bf16x8*)((char*)At + r1*128 + ((kc^(r1&7))*16));
      #pragma unroll
      for (int nf=0;nf<8;++nf){
        const int c = nf*16 + (lane&15);
        bf16x8 bf = *(const bf16x8*)((char*)Bt + c*128 + ((kc^(c&7))*16));
        acc[0][nf] = __builtin_amdgcn_mfma_f32_16x16x32_bf16(af0, bf, acc[0][nf],0,0,0);
        acc[1][nf] = __builtin_amdgcn_mfma_f32_16x16x32_bf16(af1, bf, acc[1][nf],0,0,0);
      }
    }
  }
  __syncthreads();
  short* ct = (short*)smem;                 // [128][130] bf16 (pad kills read conflicts)
  #pragma unroll
  for (int mf=0;mf<2;++mf)
    #pragma unroll
    for (int nf=0;nf<8;++nf)
      #pragma unroll
      for (int q=0;q<4;++q){
        int r = wid*32 + mf*16 + (lane>>4)*4 + q;
        int c = nf*16 + (lane&15);
        ct[r*130+c] = f2bf(acc[mf][nf][q]);
      }
  __syncthreads();
  {
    const int c = tid>>1, ih0 = (tid&1)*64;  // write HT[n0+c][m0 + ih0 .. +63]
    #pragma unroll
    for (int i8=0;i8<8;++i8){
      short v[8];
      #pragma unroll
      for (int e=0;e<8;++e) v[e] = ct[(ih0+i8*8+e)*130 + c];
      *(uint4*)(HT + (size_t)(n0+c)*NN + m0 + ih0 + i8*8) = *(const uint4*)v;
    }
  }
}

// ---------- stats: per row, masked max (via s2 monotonicity), Z, bitmask ----------
__global__ __launch_bounds__(256) void k_stats(const int* __restrict__ adj,
    const float* __restrict__ s1L, const float* __restrict__ s2L,
    unsigned long long* __restrict__ bm, float* __restrict__ rowA, float* __restrict__ rowB){
  __shared__ float s2l[NN];
  __shared__ unsigned long long bits[NN/64];
  __shared__ float red[8];
  const int tid = threadIdx.x, lane = tid&63, wid = tid>>6;
  const int row = blockIdx.x;
  for (int i=tid;i<NN/4;i+=256) ((float4*)s2l)[i] = ((const float4*)s2L)[i];
  __syncthreads();
  const int* arow = adj + (size_t)row*NN;
  float mx = -3.0e38f;
  for (int c0=0;c0<NN;c0+=256){
    int c = c0+tid;
    bool p = arow[c] > 0;
    unsigned long long msk = __ballot(p);
    if (p) mx = fmaxf(mx, s2l[c]);
    if (lane==0) bits[(c0>>6)+wid] = msk;
  }
  for (int off=32;off;off>>=1) mx = fmaxf(mx, __shfl_down(mx,off));
  if (lane==0) red[wid]=mx;
  __syncthreads();
  const float M2L = fmaxf(fmaxf(red[0],red[1]),fmaxf(red[2],red[3]));
  const float s1 = s1L[row];
  const float Lt = s1 + M2L;
  const float Lm = fmaxf(Lt, 0.2f*Lt);          // log2-domain row max (leakyrelu = max(t,0.2t))
  const float ra = s1 - Lm, rb = 0.2f*s1 - Lm;
  float z = 0.f;
  for (int c0=0;c0<NN;c0+=256){
    int c = c0+tid;
    unsigned long long wmask = bits[c>>6];
    if ((wmask>>(c&63))&1ull){
      float sv = s2l[c];
      z += exp2f(fmaxf(ra+sv, fmaf(0.2f,sv,rb)));
    }
  }
  for (int off=32;off;off>>=1) z += __shfl_down(z,off);
  if (lane==0) red[4+wid]=z;
  __syncthreads();
  if (tid==0){
    float Z = red[4]+red[5]+red[6]+red[7];
    float C = (Z > 0.f) ? (Lm + log2f(Z)) : 1.0e30f;   // Z==0 impossible (p=0.5 row)
    rowA[row] = s1 - C;
    rowB[row] = 0.2f*s1 - C;
  }
  if (tid < NN/64) bm[(size_t)row*(NN/64) + tid] = bits[tid];
}

// ---------- PV: out = elu( softmax-weights(on-the-fly) @ H ), bf16 MFMA ----------
// Tile 128(M) x 128(N), BK=64, 8 waves (16 M-rows each). A generated in registers.
__global__ __launch_bounds__(512,2) void k_pv(const short* __restrict__ HT,
    const unsigned long long* __restrict__ bm,
    const float* __restrict__ rowA, const float* __restrict__ rowB,
    const float* __restrict__ s2L, float* __restrict__ out){
  __shared__ short Bt[2][128*64];     // 2 x 16KB, XOR-swizzled [n][kchunk]
  __shared__ float s2l[NN];           // 32KB
  const int tid=threadIdx.x, lane=tid&63, wid=tid>>6;
  const int m0 = blockIdx.x*128, n0 = blockIdx.y*128;
  for (int i=tid;i<NN/4;i+=512) ((float4*)s2l)[i] = ((const float4*)s2L)[i];

  const int arow = m0 + wid*16 + (lane&15);    // this lane's attention row
  const float ra = rowA[arow], rb = rowB[arow];
  const unsigned long long* bmrow = bm + (size_t)arow*(NN/64);

  f32x4 acc[8];
  #pragma unroll
  for (int i=0;i<8;++i) acc[i] = (f32x4){0.f,0.f,0.f,0.f};

  const int sn = tid>>3, sk = tid&7;                 // staging slot (n, kchunk)
  const int swz0 = sn*128 + ((sk ^ (sn&7))*16);      // LDS byte offset, swizzled
  const size_t g0off = (size_t)(n0+sn)*NN + sk*8;
  const size_t g1off = (size_t)(n0+64+sn)*NN + sk*8;
  uint4 gb0 = *(const uint4*)(HT + g0off);
  uint4 gb1 = *(const uint4*)(HT + g1off);
  __syncthreads();                                    // s2l staged

  for (int t=0;t<128;++t){
    const int k0 = t*64;
    char* B = (char*)Bt[t&1];
    *(uint4*)(B + swz0) = gb0;
    *(uint4*)(B + 64*128 + swz0) = gb1;               // (64+sn)&7 == sn&7
    __syncthreads();
    if (t < 127){
      gb0 = *(const uint4*)(HT + g0off + k0 + 64);
      gb1 = *(const uint4*)(HT + g1off + k0 + 64);
    }
    const unsigned long long wbits = bmrow[k0>>6];
    bf16x8 af[2];
    #pragma unroll
    for (int ks=0;ks<2;++ks){
      const int kc = ks*4 + (lane>>4);                // 0..7
      const float4 sa = *(const float4*)&s2l[k0 + kc*8];
      const float4 sb = *(const float4*)&s2l[k0 + kc*8 + 4];
      const int byte = (int)((wbits >> (kc*8)) & 0xffull);
      float p[8];
      p[0]=sa.x; p[1]=sa.y; p[2]=sa.z; p[3]=sa.w;
      p[4]=sb.x; p[5]=sb.y; p[6]=sb.z; p[7]=sb.w;
      #pragma unroll
      for (int e=0;e<8;++e){
        float sv = p[e];
        float v = exp2f(fmaxf(ra+sv, fmaf(0.2f,sv,rb)));
        p[e] = ((byte>>e)&1) ? v : 0.f;
      }
      bf16x8 a;
      #pragma unroll
      for (int e=0;e<8;++e) a[e] = f2bf(p[e]);
      af[ks] = a;
    }
    #pragma unroll
    for (int nf=0;nf<8;++nf){
      const int nl = nf*16 + (lane&15);
      #pragma unroll
      for (int ks=0;ks<2;++ks){
        const int kc = ks*4 + (lane>>4);
        bf16x8 bf = *(const bf16x8*)(B + nl*128 + ((kc^(nl&7))*16));
        acc[nf] = __builtin_amdgcn_mfma_f32_16x16x32_bf16(af[ks], bf, acc[nf],0,0,0);
      }
    }
  }
  #pragma unroll
  for (int nf=0;nf<8;++nf){
    const int col = n0 + nf*16 + (lane&15);
    #pragma unroll
    for (int q=0;q<4;++q){
      const int r = m0 + wid*16 + (lane>>4)*4 + q;
      float x = acc[nf][q];
      out[(size_t)r*F + col] = (x > 0.f) ? x : expm1f(x);
    }
  }
}

extern "C" void kernel_launch(void* const* d_in, const int* in_sizes, int n_in,
                              void* d_out, int out_size, void* d_ws, size_t ws_size,
                              hipStream_t stream) {
  (void)in_sizes; (void)n_in; (void)out_size; (void)ws_size;
  const int*   adj  = (const int*)d_in[0];
  const float* X    = (const float*)d_in[1];
  const float* W    = (const float*)d_in[2];
  const float* attn = (const float*)d_in[3];
  float* out = (float*)d_out;
  char* ws = (char*)d_ws;
  short* HT  = (short*)(ws);                               // 512x8192 bf16   (8 MB)
  short* Xb  = (short*)(ws + 8388608);                     // 8192x512 bf16   (8 MB)
  short* WbT = (short*)(ws + 16777216);                    // 512x512 bf16    (0.5 MB)
  unsigned long long* bm = (unsigned long long*)(ws + 17301504); // 8192x128 u64 (8 MB)
  float* s1L = (float*)(ws + 25690112);
  float* s2L = (float*)(ws + 25722880);
  float* rowA= (float*)(ws + 25755648);
  float* rowB= (float*)(ws + 25788416);
  float* wa  = (float*)(ws + 25821184);

  k_wa    <<<dim3(2),       dim3(512), 0, stream>>>(W, attn, wa);
  k_cvt_wT<<<dim3(512),     dim3(512), 0, stream>>>(W, WbT);
  k_cvt_x <<<dim3(4096),    dim3(256), 0, stream>>>(X, Xb);
  k_s     <<<dim3(2048),    dim3(256), 0, stream>>>(X, wa, s1L, s2L);
  k_gemm1 <<<dim3(64,4),    dim3(256), 0, stream>>>(Xb, WbT, HT);
  k_stats <<<dim3(8192),    dim3(256), 0, stream>>>(adj, s1L, s2L, bm, rowA, rowB);
  k_pv    <<<dim3(64,4),    dim3(512), 0, stream>>>(HT, bm, rowA, rowB, s2L, out);
}

// Round 2
// 238.577 us; speedup vs baseline: 1.7518x; 1.7518x over previous
//
#include <hip/hip_runtime.h>
#include <hip/hip_bf16.h>
#include <cstdint>

#define NN 8192
#define F 512
#define LOG2E 1.4426950408889634f

typedef __attribute__((ext_vector_type(8))) short bf16x8;
typedef __attribute__((ext_vector_type(4))) float f32x4;
typedef unsigned int uint32;
typedef unsigned long long u64;

__device__ __forceinline__ short f2bf(float x){
  __hip_bfloat16 h = __float2bfloat16(x);
  return *reinterpret_cast<short*>(&h);
}

// ---------- wa = W @ a1 / W @ a2 : one wave per output element ----------
__global__ __launch_bounds__(256) void k_wa(const float* __restrict__ W, const float* __restrict__ attn,
                     float* __restrict__ wa){
  const int lane = threadIdx.x&63, wid = threadIdx.x>>6;
  const int id = blockIdx.x*4 + wid;       // 0..1023 : b = id>>9, c = id&511
  const int b = id>>9, c = id&511;
  const float4* Wr = (const float4*)(W + (size_t)c*F);
  const float4* av = (const float4*)(attn + b*F);
  float s = 0.f;
  #pragma unroll
  for (int h=0;h<2;++h){
    const int k = lane + h*64;
    const float4 wv = Wr[k], a = av[k];
    s += wv.x*a.x + wv.y*a.y + wv.z*a.z + wv.w*a.w;
  }
  for (int off=32;off;off>>=1) s += __shfl_down(s,off);
  if (lane==0) wa[id] = s;
}

// ---------- W^T -> bf16 via LDS tile ----------
__global__ __launch_bounds__(256) void k_tw(const float* __restrict__ W, short* __restrict__ WbT){
  __shared__ short t[64][72];
  const int k0 = blockIdx.x*64, n0 = blockIdx.y*64;
  #pragma unroll
  for (int it=0;it<16;++it){
    const int idx = it*256 + threadIdx.x;
    const int r = idx>>6, c = idx&63;
    t[r][c] = f2bf(W[(size_t)(k0+r)*F + n0 + c]);
  }
  __syncthreads();
  #pragma unroll
  for (int it=0;it<2;++it){
    const int idx = it*256 + threadIdx.x;
    const int n = idx>>3, g = idx&7;
    short v[8];
    #pragma unroll
    for (int e=0;e<8;++e) v[e] = t[g*8+e][n];
    *(uint4*)(WbT + (size_t)(n0+n)*F + k0 + g*8) = *(const uint4*)v;
  }
}

// ---------- fused: s1L + u/w tables + X->bf16 ; one wave per row ----------
__global__ __launch_bounds__(256) void k_prep(const float* __restrict__ X, const float* __restrict__ wa,
    short* __restrict__ Xb, float* __restrict__ s1L, float2* __restrict__ uwf, uint32* __restrict__ uwb){
  const int lane = threadIdx.x&63, wid = threadIdx.x>>6;
  const int row = blockIdx.x*4 + wid;
  const float4* X4 = (const float4*)(X + (size_t)row*F);
  const float4* A4 = (const float4*)wa;
  const float4* B4 = (const float4*)(wa + F);
  uint2* Xb4 = (uint2*)(Xb + (size_t)row*F);
  float a1 = 0.f, a2 = 0.f;
  #pragma unroll
  for (int h=0;h<2;++h){
    const int c = lane + h*64;
    const float4 x = X4[c];
    const float4 a = A4[c];
    const float4 b = B4[c];
    a1 += x.x*a.x + x.y*a.y + x.z*a.z + x.w*a.w;
    a2 += x.x*b.x + x.y*b.y + x.z*b.z + x.w*b.w;
    short o[4] = {f2bf(x.x),f2bf(x.y),f2bf(x.z),f2bf(x.w)};
    Xb4[c] = *(const uint2*)o;
  }
  for (int off=32;off;off>>=1){ a1 += __shfl_down(a1,off); a2 += __shfl_down(a2,off); }
  if (lane==0){
    const float s1 = a1*LOG2E, s2 = a2*LOG2E;
    s1L[row] = s1;
    const float u = exp2f(s2), w = exp2f(0.2f*s2);
    uwf[row] = make_float2(u, w);
    uwb[row] = (uint32)(unsigned short)f2bf(u) | ((uint32)(unsigned short)f2bf(w)<<16);
  }
}

// ---------- GEMM1: h = Xb @ WbT^T, writes HT[feature][node] bf16 ----------
__global__ __launch_bounds__(256,2) void k_gemm1(const short* __restrict__ Xb,
    const short* __restrict__ WbT, short* __restrict__ HT){
  __shared__ char smem[33280];
  short* At = (short*)smem;
  short* Bt = (short*)(smem + 16384);
  const int tid=threadIdx.x, lane=tid&63, wid=tid>>6;
  const int m0 = blockIdx.x*128, n0 = blockIdx.y*128;
  f32x4 acc[2][8];
  #pragma unroll
  for (int a=0;a<2;++a)
    #pragma unroll
    for (int b=0;b<8;++b) acc[a][b] = (f32x4){0.f,0.f,0.f,0.f};

  for (int t=0;t<8;++t){
    const int k0 = t*64;
    __syncthreads();
    #pragma unroll
    for (int rnd=0;rnd<4;++rnd){
      const int s = rnd*256 + tid;
      const int n = s>>3, kc = s&7;
      uint4 va = *(const uint4*)(Xb  + (size_t)(m0+n)*F + k0 + kc*8);
      uint4 vb = *(const uint4*)(WbT + (size_t)(n0+n)*F + k0 + kc*8);
      const int off = n*128 + ((kc^(n&7))*16);
      *(uint4*)((char*)At + off) = va;
      *(uint4*)((char*)Bt + off) = vb;
    }
    __syncthreads();
    #pragma unroll
    for (int ks=0;ks<2;++ks){
      const int kc = ks*4 + (lane>>4);
      int r0 = wid*32 + (lane&15);
      int r1 = r0 + 16;
      bf16x8 af0 = *(const bf16x8*)((char*)At + r0*128 + ((kc^(r0&7))*16));
      bf16x8 af1 = *(const bf16x8*)((char*)At + r1*128 + ((kc^(r1&7))*16));
      #pragma unroll
      for (int nf=0;nf<8;++nf){
        const int c = nf*16 + (lane&15);
        bf16x8 bf = *(const bf16x8*)((char*)Bt + c*128 + ((kc^(c&7))*16));
        acc[0][nf] = __builtin_amdgcn_mfma_f32_16x16x32_bf16(af0, bf, acc[0][nf],0,0,0);
        acc[1][nf] = __builtin_amdgcn_mfma_f32_16x16x32_bf16(af1, bf, acc[1][nf],0,0,0);
      }
    }
  }
  __syncthreads();
  short* ct = (short*)smem;                 // [128][130] bf16
  #pragma unroll
  for (int mf=0;mf<2;++mf)
    #pragma unroll
    for (int nf=0;nf<8;++nf)
      #pragma unroll
      for (int q=0;q<4;++q){
        int r = wid*32 + mf*16 + (lane>>4)*4 + q;
        int c = nf*16 + (lane&15);
        ct[r*130+c] = f2bf(acc[mf][nf][q]);
      }
  __syncthreads();
  {
    const int c = tid>>1, ih0 = (tid&1)*64;
    #pragma unroll
    for (int i8=0;i8<8;++i8){
      short v[8];
      #pragma unroll
      for (int e=0;e<8;++e) v[e] = ct[(ih0+i8*8+e)*130 + c];
      *(uint4*)(HT + (size_t)(n0+c)*NN + m0 + ih0 + i8*8) = *(const uint4*)v;
    }
  }
}

// ---------- stats: single pass, contiguous int4 loads, no transcendentals ----------
__global__ __launch_bounds__(256) void k_stats(const int* __restrict__ adj,
    const float* __restrict__ s1L, const float* __restrict__ uwf,
    uint32* __restrict__ bm32, float2* __restrict__ rowE2){
  __shared__ unsigned char nib[2048];
  __shared__ float zred[4];
  const int tid=threadIdx.x, lane=tid&63, wid=tid>>6;
  const int row = blockIdx.x;
  const float s1 = s1L[row];
  const float A0 = exp2f(s1), B0 = exp2f(0.2f*s1);
  const int4* a4 = (const int4*)(adj + (size_t)row*NN);
  const float4* uw4 = (const float4*)uwf;
  float z = 0.f;
  #pragma unroll
  for (int it=0;it<8;++it){
    const int c4 = it*256 + tid;           // covers cols 4*c4 .. 4*c4+3
    const int4 a = a4[c4];
    const float4 p0 = uw4[c4*2];
    const float4 p1 = uw4[c4*2+1];
    const float t0 = fmaxf(A0*p0.x, B0*p0.y);
    const float t1 = fmaxf(A0*p0.z, B0*p0.w);
    const float t2 = fmaxf(A0*p1.x, B0*p1.y);
    const float t3 = fmaxf(A0*p1.z, B0*p1.w);
    const int b0 = a.x>0, b1 = a.y>0, b2 = a.z>0, b3 = a.w>0;
    z += b0 ? t0 : 0.f;
    z += b1 ? t1 : 0.f;
    z += b2 ? t2 : 0.f;
    z += b3 ? t3 : 0.f;
    nib[c4] = (unsigned char)(b0 | (b1<<1) | (b2<<2) | (b3<<3));
  }
  for (int off=32;off;off>>=1) z += __shfl_down(z,off);
  if (lane==0) zred[wid] = z;
  __syncthreads();
  {
    const u64 nv = *(const u64*)&nib[tid*8];
    uint32 m = 0;
    #pragma unroll
    for (int i=0;i<8;++i) m |= ((uint32)((nv>>(8*i)) & 0xFull)) << (4*i);
    bm32[(size_t)row*256 + tid] = m;       // word tid = cols 32*tid .. +31
  }
  if (tid==0){
    const float Z = zred[0]+zred[1]+zred[2]+zred[3];
    const float inv = 1.f/Z;
    rowE2[row] = make_float2(A0*inv, B0*inv);
  }
}

// ---------- PV: out = elu( softmax-weights(on-the-fly) @ H ) ----------
__global__ __launch_bounds__(512,4) void k_pv(const short* __restrict__ HT,
    const uint32* __restrict__ bm32, const float2* __restrict__ rowE2,
    const uint32* __restrict__ uwb, float* __restrict__ out){
  __shared__ short Bt[2][128*64];     // 2 x 16KB, XOR-swizzled
  __shared__ uint32 uwl[NN];          // 32KB packed bf16 (u,w)
  const int tid=threadIdx.x, lane=tid&63, wid=tid>>6;
  const int m0 = blockIdx.x*128, n0 = blockIdx.y*128;
  for (int i=tid;i<NN/4;i+=512) ((uint4*)uwl)[i] = ((const uint4*)uwb)[i];

  const int arow = m0 + wid*16 + (lane&15);
  const float2 E = rowE2[arow];
  const float EA = E.x, EB = E.y;
  const u64* bmrow = (const u64*)(bm32 + (size_t)arow*(NN/32));

  f32x4 acc[8];
  #pragma unroll
  for (int i=0;i<8;++i) acc[i] = (f32x4){0.f,0.f,0.f,0.f};

  const int sn = tid>>3, sk = tid&7;
  const int swz0 = sn*128 + ((sk ^ (sn&7))*16);
  const size_t g0off = (size_t)(n0+sn)*NN + sk*8;
  const size_t g1off = (size_t)(n0+64+sn)*NN + sk*8;
  uint4 gb0 = *(const uint4*)(HT + g0off);
  uint4 gb1 = *(const uint4*)(HT + g1off);
  __syncthreads();

  for (int t=0;t<128;++t){
    const int k0 = t*64;
    char* B = (char*)Bt[t&1];
    *(uint4*)(B + swz0) = gb0;
    *(uint4*)(B + 64*128 + swz0) = gb1;
    __syncthreads();
    if (t < 127){
      gb0 = *(const uint4*)(HT + g0off + k0 + 64);
      gb1 = *(const uint4*)(HT + g1off + k0 + 64);
    }
    const u64 wbits = bmrow[t];
    bf16x8 af[2];
    #pragma unroll
    for (int ks=0;ks<2;++ks){
      const int kc = ks*4 + (lane>>4);
      const uint4 q0 = *(const uint4*)&uwl[k0 + kc*8];
      const uint4 q1 = *(const uint4*)&uwl[k0 + kc*8 + 4];
      const int mb = (int)((wbits >> (kc*8)) & 0xffull);
      const uint32 qa[8] = {q0.x,q0.y,q0.z,q0.w,q1.x,q1.y,q1.z,q1.w};
      short a[8];
      #pragma unroll
      for (int e=0;e<8;++e){
        const float u = __uint_as_float(qa[e]<<16);
        const float w = __uint_as_float(qa[e]&0xffff0000u);
        float v = fmaxf(EA*u, EB*w);
        v = ((mb>>e)&1) ? v : 0.f;
        a[e] = f2bf(v);
      }
      af[ks] = *(const bf16x8*)a;
    }
    #pragma unroll
    for (int nf=0;nf<8;++nf){
      const int nl = nf*16 + (lane&15);
      #pragma unroll
      for (int ks=0;ks<2;++ks){
        const int kc = ks*4 + (lane>>4);
        bf16x8 bf = *(const bf16x8*)(B + nl*128 + ((kc^(nl&7))*16));
        acc[nf] = __builtin_amdgcn_mfma_f32_16x16x32_bf16(af[ks], bf, acc[nf],0,0,0);
      }
    }
  }
  #pragma unroll
  for (int nf=0;nf<8;++nf){
    const int col = n0 + nf*16 + (lane&15);
    #pragma unroll
    for (int q=0;q<4;++q){
      const int r = m0 + wid*16 + (lane>>4)*4 + q;
      const float x = acc[nf][q];
      out[(size_t)r*F + col] = (x > 0.f) ? x : expm1f(x);
    }
  }
}

extern "C" void kernel_launch(void* const* d_in, const int* in_sizes, int n_in,
                              void* d_out, int out_size, void* d_ws, size_t ws_size,
                              hipStream_t stream) {
  (void)in_sizes; (void)n_in; (void)out_size; (void)ws_size;
  const int*   adj  = (const int*)d_in[0];
  const float* X    = (const float*)d_in[1];
  const float* W    = (const float*)d_in[2];
  const float* attn = (const float*)d_in[3];
  float* out = (float*)d_out;
  char* ws = (char*)d_ws;
  short*  HT   = (short*)(ws);                      // 8 MB
  short*  Xb   = (short*)(ws + 8388608);            // 8 MB
  short*  WbT  = (short*)(ws + 16777216);           // 0.5 MB
  uint32* bm32 = (uint32*)(ws + 17301504);          // 8 MB
  float*  s1L  = (float*)(ws + 25690112);           // 32 KB
  float*  uwf  = (float*)(ws + 25722880);           // 64 KB (float2)
  uint32* uwb  = (uint32*)(ws + 25788416);          // 32 KB
  float2* rowE2= (float2*)(ws + 25821184);          // 64 KB
  float*  wa   = (float*)(ws + 25886720);           // 4 KB

  k_wa   <<<dim3(256),  dim3(256), 0, stream>>>(W, attn, wa);
  k_tw   <<<dim3(8,8),  dim3(256), 0, stream>>>(W, WbT);
  k_prep <<<dim3(2048), dim3(256), 0, stream>>>(X, wa, Xb, s1L, (float2*)uwf, uwb);
  k_gemm1<<<dim3(64,4), dim3(256), 0, stream>>>(Xb, WbT, HT);
  k_stats<<<dim3(8192), dim3(256), 0, stream>>>(adj, s1L, uwf, bm32, rowE2);
  k_pv   <<<dim3(64,4), dim3(512), 0, stream>>>(HT, bm32, rowE2, uwb, out);
}